// Round 4
// baseline (825.362 us; speedup 1.0000x reference)
//
#include <hip/hip_runtime.h>
#include <hip/hip_cooperative_groups.h>
#include <hip/hip_bf16.h>
#include <stdint.h>

namespace cg = cooperative_groups;

// SparseSwiGLU on MI355X: fine-band radix densify -> bf16 weights -> MFMA GEMMs.
// R17: ONE cooperative kernel (grid 1024x256, grid.sync between phases)
// replaces the 4-dispatch serial chain. Evidence: four structurally different
// GEMM schedules (R13-R16) all produced 133-139us => the K-loops are not the
// cost; the serial launch+drain boundaries and phase interiors are. Phases:
//   P1 bin(768 blocks) + x-prep(256)        (same bodies as R12)
//   P2 build WUP/WGATE (1024 = 2mat x 256band x 2half, 8 rows/block)
//   P3 upgate GEMM (512, XCD-grouped roles) || build WDOWN (512)
//   P4 down GEMM split-K=8 (1024, XCD-grouped roles)
// Max LDS 36KB -> 4 blocks/CU -> all 1024 blocks co-resident (coop-launch
// requirement). __launch_bounds__(256,4) caps VGPR at 128. Fallback to the
// R16 4-kernel path if the cooperative launch is rejected.
//
// Workspace layout (<= 68 MB):
//   [0,    8MB)  WUP    bf16 [4096][1024]   (B^T, K-contiguous)
//   [8MB, 16MB)  WGATE  bf16 [4096][1024]
//   [16MB,24MB)  WDOWN  bf16 [1024][4096]
//   [24MB,25MB)  XB     bf16 [512][1024]
//   [25MB,29MB)  HID    bf16 [512][4096]
//   [29MB,+9MB)  BANDS  uint[3][256 band][256 chunk][12 slot]
//   [66MB,+768K) CNT    int[3][256][256]
//   [67MB,+12B)  GOC    int[3]              overflow counters
//   [67MB+64,..) GOF    uint2[3][4096]      overflow entries (band, packed)

#define DIM_    1024
#define HIDDEN_ 4096
#define NNZ_    262144
#define TTOK_   512
#define PADL_   12              // 48 B segments; P(X>12|lam=4) ~ 2.7e-4

typedef __attribute__((ext_vector_type(8))) short short8;
typedef __attribute__((ext_vector_type(4))) float float4v;

__device__ inline unsigned short f2bf(float f) {
    union { float f; unsigned int u; } c; c.f = f;
    unsigned int u = c.u;
    unsigned int r = u + 0x7fffu + ((u >> 16) & 1u);   // RNE
    return (unsigned short)(r >> 16);
}

__device__ inline void async16(const unsigned short* g, unsigned short* l) {
    __builtin_amdgcn_global_load_lds(
        (const __attribute__((address_space(1))) unsigned int*)g,
        (__attribute__((address_space(3))) unsigned int*)l, 16, 0, 0);
}

// Counted-vmcnt pipeline barrier (R15/R16): wait for all but N outstanding
// global_load_lds, then block barrier. sched_barrier(0) pins code motion.
#define PIPE_BAR(N)                                                         \
    __builtin_amdgcn_sched_barrier(0);                                      \
    asm volatile("s_waitcnt vmcnt(" #N ") lgkmcnt(0)" ::: "memory");        \
    __builtin_amdgcn_s_barrier();                                           \
    __builtin_amdgcn_sched_barrier(0);

#define XC_ ((TTOK_ * DIM_) / 4)           // 131072 float4 units

// ---- shared GEMM macros (used by mega kernel AND fallback kernels) ----
#define STAGE_UG(buf, k0)                                      \
    async16(gA + (k0),  sA_  + (buf) * 2048 + t * 8);          \
    async16(gBu + (k0), sBu_ + (buf) * 2048 + t * 8);          \
    async16(gBg + (k0), sBg_ + (buf) * 2048 + t * 8);

#define COMPUTE_UG(buf)                                                        \
    {                                                                          \
        const int kb = (buf) * 2048 + lkq * 8;                                 \
        short8 a[2], bu[2], bg[2];                                             \
        _Pragma("unroll")                                                      \
        for (int im = 0; im < 2; ++im)                                         \
            a[im] = *(const short8*)&sA_[kb + (wm + im * 16 + lr) * 32];       \
        _Pragma("unroll")                                                      \
        for (int in = 0; in < 2; ++in) {                                       \
            bu[in] = *(const short8*)&sBu_[kb + (wn + in * 16 + lr) * 32];     \
            bg[in] = *(const short8*)&sBg_[kb + (wn + in * 16 + lr) * 32];     \
        }                                                                      \
        _Pragma("unroll")                                                      \
        for (int im = 0; im < 2; ++im)                                         \
            _Pragma("unroll")                                                  \
            for (int in = 0; in < 2; ++in) {                                   \
                au[im][in] = __builtin_amdgcn_mfma_f32_16x16x32_bf16(          \
                    a[im], bu[in], au[im][in], 0, 0, 0);                       \
                ag[im][in] = __builtin_amdgcn_mfma_f32_16x16x32_bf16(          \
                    a[im], bg[in], ag[im][in], 0, 0, 0);                       \
            }                                                                  \
    }

#define STAGE_DN(buf, k0)                                      \
    async16(gA + (k0), sA + (buf) * 2048 + t * 8);             \
    async16(gB + (k0), sB + (buf) * 2048 + t * 8);

#define COMPUTE_DN(buf)                                                        \
    {                                                                          \
        const int kb = (buf) * 2048 + lkq * 8;                                 \
        short8 a[2], b2[2];                                                    \
        _Pragma("unroll")                                                      \
        for (int im = 0; im < 2; ++im)                                         \
            a[im] = *(const short8*)&sA[kb + (wm + im * 16 + lr) * 32];        \
        _Pragma("unroll")                                                      \
        for (int in = 0; in < 2; ++in)                                         \
            b2[in] = *(const short8*)&sB[kb + (wn + in * 16 + lr) * 32];       \
        _Pragma("unroll")                                                      \
        for (int im = 0; im < 2; ++im)                                         \
            _Pragma("unroll")                                                  \
            for (int in = 0; in < 2; ++in)                                     \
                acc[im][in] = __builtin_amdgcn_mfma_f32_16x16x32_bf16(         \
                    a[im], b2[in], acc[im][in], 0, 0, 0);                      \
    }

// ================================================================ mega kernel
__global__ __launch_bounds__(256, 4) void mega_kernel(
    const int* __restrict__ ur, const int* __restrict__ uc, const float* __restrict__ uv,
    const int* __restrict__ gr, const int* __restrict__ gc, const float* __restrict__ gv,
    const int* __restrict__ dr, const int* __restrict__ dc, const float* __restrict__ dv,
    const float* __restrict__ x,
    const float* __restrict__ up_bias, const float* __restrict__ gate_bias,
    unsigned short* __restrict__ WUP, unsigned short* __restrict__ WGATE,
    unsigned short* __restrict__ WDOWN, unsigned short* __restrict__ XB,
    unsigned short* __restrict__ HID,
    unsigned int* __restrict__ BANDS, int* __restrict__ CNT,
    int* __restrict__ GOC, uint2* __restrict__ GOF,
    const float* __restrict__ down_bias,
    float* __restrict__ out)
{
    cg::grid_group grid = cg::this_grid();
    __shared__ __align__(16) unsigned char smem[36864];   // 36 KB, reused per phase
    const int b = blockIdx.x;
    const int t = threadIdx.x;
    const int w = t >> 6, l = t & 63;
    const int wm = (w >> 1) * 32, wn = (w & 1) * 32;
    const int lr = l & 15, lkq = l >> 4;

    // ================= phase 1: bin (b<768) + prep (b>=768) =================
    if (b >= 768) {
        const unsigned int u0 = (unsigned int)(b - 768) * 1024u + (unsigned int)t * 4u;
        #pragma unroll
        for (int q = 0; q < 4; ++q) {
            const unsigned int id = u0 + q;
            if (id < XC_) {
                float4 v = ((const float4*)x)[id];
                ushort4 o;
                o.x = f2bf(v.x); o.y = f2bf(v.y); o.z = f2bf(v.z); o.w = f2bf(v.w);
                ((ushort4*)XB)[id] = o;
            } else {
                const unsigned int i = id - XC_;
                float4 v = ((const float4*)x)[i];
                const int d = (i * 4) & (DIM_ - 1);
                const float4 bb = *(const float4*)(down_bias + d);
                float4 o;
                o.x = v.x + bb.x; o.y = v.y + bb.y; o.z = v.z + bb.z; o.w = v.w + bb.w;
                ((float4*)out)[i] = o;
            }
        }
    } else {
        unsigned int (*stage)[PADL_] = (unsigned int (*)[PADL_])smem;   // 12 KB
        int* lcount = (int*)(smem + 12288);                             // 1 KB
        const int mat = b >> 8;          // 0 up, 1 gate, 2 down
        const int chunk = b & 255;
        const int*   rs = (mat == 0) ? ur : (mat == 1) ? gr : dr;
        const int*   cs = (mat == 0) ? uc : (mat == 1) ? gc : dc;
        const float* vs = (mat == 0) ? uv : (mat == 1) ? gv : dv;
        const int shift = (mat == 2) ? 2 : 4;   // rows/band: 4 (down), 16 (up/gate)
        const int rmask = (mat == 2) ? 3 : 15;
        lcount[t] = 0;
        __syncthreads();

        const int base = chunk * 1024 + t * 4;
        int4   r4 = *(const int4*)(rs + base);
        int4   c4 = *(const int4*)(cs + base);
        float4 v4 = *(const float4*)(vs + base);
        int   rrv[4] = {r4.x, r4.y, r4.z, r4.w};
        int   ccv[4] = {c4.x, c4.y, c4.z, c4.w};
        float vvv[4] = {v4.x, v4.y, v4.z, v4.w};
        #pragma unroll
        for (int jj = 0; jj < 4; ++jj) {
            const int band = rrv[jj] >> shift;
            const unsigned int e = ((unsigned int)(rrv[jj] & rmask) << 28)
                                 | ((unsigned int)ccv[jj] << 16)
                                 | (unsigned int)f2bf(vvv[jj]);
            const int pos = atomicAdd(&lcount[band], 1);
            if (pos < PADL_) {
                stage[band][pos] = e;
            } else {
                const int op = atomicAdd(&GOC[mat], 1);
                GOF[mat * 4096 + op] = make_uint2((unsigned int)band, e);
            }
        }
        __syncthreads();
        unsigned int* seg = BANDS + ((unsigned int)(mat * 256 + t) * 256 + chunk) * PADL_;
        const uint4* sp = (const uint4*)&stage[t][0];
        *(uint4*)(seg)     = sp[0];
        *(uint4*)(seg + 4) = sp[1];
        *(uint4*)(seg + 8) = sp[2];
        CNT[(mat * 256 + t) * 256 + chunk] = lcount[t];
    }
    __threadfence();
    grid.sync();

    // ================= phase 2: build WUP/WGATE (8 rows/block) =================
    {
        float* acc = (float*)smem;                       // 32 KB
        const int mat = b >> 9;                          // 0 up, 1 gate
        const int rem = b & 511;
        const int band = rem >> 1;
        const int hb = rem & 1;
        unsigned short* outw = (mat ? WGATE : WUP) + (band * 16 + hb * 8) * 1024;
        const unsigned int rbase = hb * 8;
        #pragma unroll
        for (int k = 0; k < 8; ++k)
            *(float4*)&acc[(k * 256 + t) * 4] = make_float4(0.f, 0.f, 0.f, 0.f);
        __syncthreads();

        const unsigned int* seg =
            BANDS + ((unsigned int)(mat * 256 + band) * 256 + t) * PADL_;
        const int c = CNT[(mat * 256 + band) * 256 + t];
        uint4 q[3];
        const uint4* sp = (const uint4*)seg;
        #pragma unroll
        for (int i = 0; i < 3; ++i) q[i] = sp[i];
        const unsigned int* qq = (const unsigned int*)q;
        #pragma unroll
        for (int jj = 0; jj < PADL_; ++jj) {
            const unsigned int e = qq[jj];
            const unsigned int r2 = (e >> 28) - rbase;   // unsigned wrap filter
            if (jj < c && r2 < 8u)
                atomicAdd(&acc[r2 * 1024 + ((e >> 16) & 0xFFFu)],
                          __uint_as_float(e << 16));
        }
        const int oc = GOC[mat] < 4096 ? GOC[mat] : 4096;
        for (int i = t; i < oc; i += 256) {
            uint2 oe = GOF[mat * 4096 + i];
            if ((int)oe.x == band) {
                const unsigned int e = oe.y;
                const unsigned int r2 = (e >> 28) - rbase;
                if (r2 < 8u)
                    atomicAdd(&acc[r2 * 1024 + ((e >> 16) & 0xFFFu)],
                              __uint_as_float(e << 16));
            }
        }
        __syncthreads();
        #pragma unroll
        for (int k = 0; k < 8; ++k) {
            const int cc = (k * 256 + t) * 4;
            ushort4 o;
            o.x = f2bf(acc[cc]);     o.y = f2bf(acc[cc + 1]);
            o.z = f2bf(acc[cc + 2]); o.w = f2bf(acc[cc + 3]);
            *(ushort4*)(outw + cc) = o;
        }
    }
    __threadfence();
    grid.sync();

    // ========= phase 3: upgate GEMM (b<512) || build WDOWN (b>=512) =========
    if (b < 512) {
        unsigned short* sA_  = (unsigned short*)smem;    // [3][2048]
        unsigned short* sBu_ = sA_ + 3 * 2048;
        unsigned short* sBg_ = sA_ + 6 * 2048;
        // XCD-grouped role: blocks with the same (b&7) share an XCD (round-
        // robin dispatch); give each XCD 8 n-panels x 8 m -> weight panels
        // (2MB) become L2-resident per XCD.
        const int xg = b & 7, j = b >> 3;
        const int n0 = (xg * 8 + (j & 7)) * 64;
        const int m0 = (j >> 3) * 64;

        float4v au[2][2], ag[2][2];
        for (int im = 0; im < 2; ++im)
            for (int in = 0; in < 2; ++in) {
                au[im][in] = float4v{0.f, 0.f, 0.f, 0.f};
                ag[im][in] = float4v{0.f, 0.f, 0.f, 0.f};
            }

        const int srow = t >> 2, scol = (t & 3) * 8;
        const unsigned short* gA  = XB    + (m0 + srow) * DIM_ + scol;
        const unsigned short* gBu = WUP   + (n0 + srow) * DIM_ + scol;
        const unsigned short* gBg = WGATE + (n0 + srow) * DIM_ + scol;

        STAGE_UG(0, 0);
        STAGE_UG(1, 32);
        int cur = 0;
        for (int k0 = 64; k0 < DIM_; k0 += 32) {      // 30 iterations
            PIPE_BAR(3);
            const int nnb = cur == 0 ? 2 : cur - 1;
            STAGE_UG(nnb, k0);
            COMPUTE_UG(cur);
            cur = cur == 2 ? 0 : cur + 1;
        }
        PIPE_BAR(3);
        COMPUTE_UG(cur);
        cur = cur == 2 ? 0 : cur + 1;
        PIPE_BAR(0);
        COMPUTE_UG(cur);

        for (int im = 0; im < 2; ++im) {
            for (int in = 0; in < 2; ++in) {
                const int n = n0 + wn + in * 16 + lr;
                const float ub = up_bias[n], gb = gate_bias[n];
                for (int r = 0; r < 4; ++r) {
                    const int m = m0 + wm + im * 16 + lkq * 4 + r;
                    const float u = au[im][in][r] + ub;
                    const float g = ag[im][in][r] + gb;
                    const float h = (u / (1.f + __expf(-u))) * g;
                    HID[m * HIDDEN_ + n] = f2bf(h);
                }
            }
        }
    } else {
        // ---- build WDOWN: band half (2 rows of 4096); 32KB acc ----
        float* acc = (float*)smem;
        const int rem = b - 512;
        const int band = rem >> 1;
        const int hb = rem & 1;
        const unsigned int rbase = hb * 2;
        unsigned short* outw = WDOWN + (band * 4 + hb * 2) * 4096;

        #pragma unroll
        for (int k = 0; k < 8; ++k)
            *(float4*)&acc[(k * 256 + t) * 4] = make_float4(0.f, 0.f, 0.f, 0.f);
        __syncthreads();

        const unsigned int* seg =
            BANDS + ((unsigned int)(2 * 256 + band) * 256 + t) * PADL_;
        const int c = CNT[(2 * 256 + band) * 256 + t];
        uint4 q[3];
        const uint4* sp = (const uint4*)seg;
        #pragma unroll
        for (int i = 0; i < 3; ++i) q[i] = sp[i];
        const unsigned int* qq = (const unsigned int*)q;
        #pragma unroll
        for (int jj = 0; jj < PADL_; ++jj) {
            const unsigned int e = qq[jj];
            const unsigned int r2 = (e >> 28) - rbase;
            if (jj < c && r2 < 2u)
                atomicAdd(&acc[r2 * 4096 + ((e >> 16) & 0xFFFu)],
                          __uint_as_float(e << 16));
        }
        const int oc = GOC[2] < 4096 ? GOC[2] : 4096;
        for (int i = t; i < oc; i += 256) {
            uint2 oe = GOF[2 * 4096 + i];
            if ((int)oe.x == band) {
                const unsigned int e = oe.y;
                const unsigned int r2 = (e >> 28) - rbase;
                if (r2 < 2u)
                    atomicAdd(&acc[r2 * 4096 + ((e >> 16) & 0xFFFu)],
                              __uint_as_float(e << 16));
            }
        }
        __syncthreads();
        #pragma unroll
        for (int k = 0; k < 8; ++k) {
            const int cc = (k * 256 + t) * 4;
            ushort4 o;
            o.x = f2bf(acc[cc]);     o.y = f2bf(acc[cc + 1]);
            o.z = f2bf(acc[cc + 2]); o.w = f2bf(acc[cc + 3]);
            *(ushort4*)(outw + cc) = o;
        }
    }
    __threadfence();
    grid.sync();

    // ================= phase 4: down GEMM, split-K = 8 =================
    {
        unsigned short* sA = (unsigned short*)smem;      // [3][2048]
        unsigned short* sB = sA + 3 * 2048;
        // XCD-grouped: each XCD owns 2 n-panels; its WDOWN slice (1MB) stays L2.
        const int xcd = b & 7, j = b >> 3;               // j in [0,128)
        const int n0 = (xcd * 2 + (j & 1)) * 64;
        const int m0 = ((j >> 1) & 7) * 64;
        const int kb0 = (j >> 4) * 512;

        float4v acc[2][2];
        for (int im = 0; im < 2; ++im)
            for (int in = 0; in < 2; ++in)
                acc[im][in] = float4v{0.f, 0.f, 0.f, 0.f};

        const int srow = t >> 2, scol = (t & 3) * 8;
        const unsigned short* gA = HID   + (m0 + srow) * HIDDEN_ + scol;
        const unsigned short* gB = WDOWN + (n0 + srow) * HIDDEN_ + scol;

        STAGE_DN(0, kb0);
        STAGE_DN(1, kb0 + 32);
        int cur = 0;
        for (int k0 = kb0 + 64; k0 < kb0 + 512; k0 += 32) {   // 14 iterations
            PIPE_BAR(2);
            const int nnb = cur == 0 ? 2 : cur - 1;
            STAGE_DN(nnb, k0);
            COMPUTE_DN(cur);
            cur = cur == 2 ? 0 : cur + 1;
        }
        PIPE_BAR(2);
        COMPUTE_DN(cur);
        cur = cur == 2 ? 0 : cur + 1;
        PIPE_BAR(0);
        COMPUTE_DN(cur);

        for (int im = 0; im < 2; ++im) {
            for (int in = 0; in < 2; ++in) {
                const int n = n0 + wn + in * 16 + lr;
                for (int r = 0; r < 4; ++r) {
                    const int m = m0 + wm + im * 16 + lkq * 4 + r;
                    atomicAdd(out + m * DIM_ + n, acc[im][in][r]);
                }
            }
        }
    }
}

// ================================================================ fallback path
// Verbatim R16 kernels (passed correctness) — used only if the cooperative
// launch is rejected by the runtime/graph-capture.

__global__ __launch_bounds__(256) void bin_prep_kernel(
    const int* __restrict__ ur, const int* __restrict__ uc, const float* __restrict__ uv,
    const int* __restrict__ gr, const int* __restrict__ gc, const float* __restrict__ gv,
    const int* __restrict__ dr, const int* __restrict__ dc, const float* __restrict__ dv,
    const float* __restrict__ x, const float* __restrict__ down_bias,
    unsigned int* __restrict__ bands, int* __restrict__ cnt,
    int* __restrict__ goc, uint2* __restrict__ gof,
    unsigned short* __restrict__ xb, float* __restrict__ out) {
    const int b = blockIdx.x;
    const int t = threadIdx.x;
    if (b >= 768) {
        const unsigned int u0 = (b - 768) * 1024 + t * 4;
        #pragma unroll
        for (int q = 0; q < 4; ++q) {
            const unsigned int id = u0 + q;
            if (id < XC_) {
                float4 v = ((const float4*)x)[id];
                ushort4 o;
                o.x = f2bf(v.x); o.y = f2bf(v.y); o.z = f2bf(v.z); o.w = f2bf(v.w);
                ((ushort4*)xb)[id] = o;
            } else {
                const unsigned int i = id - XC_;
                float4 v = ((const float4*)x)[i];
                const int d = (i * 4) & (DIM_ - 1);
                const float4 bb = *(const float4*)(down_bias + d);
                float4 o;
                o.x = v.x + bb.x; o.y = v.y + bb.y; o.z = v.z + bb.z; o.w = v.w + bb.w;
                ((float4*)out)[i] = o;
            }
        }
        return;
    }
    __shared__ unsigned int stage[256][PADL_];
    __shared__ int lcount[256];
    const int mat = b >> 8;
    const int chunk = b & 255;
    const int*   rs = (mat == 0) ? ur : (mat == 1) ? gr : dr;
    const int*   cs = (mat == 0) ? uc : (mat == 1) ? gc : dc;
    const float* vs = (mat == 0) ? uv : (mat == 1) ? gv : dv;
    const int shift = (mat == 2) ? 2 : 4;
    const int rmask = (mat == 2) ? 3 : 15;
    lcount[t] = 0;
    __syncthreads();

    const int base = chunk * 1024 + t * 4;
    int4   r4 = *(const int4*)(rs + base);
    int4   c4 = *(const int4*)(cs + base);
    float4 v4 = *(const float4*)(vs + base);
    int   rr[4] = {r4.x, r4.y, r4.z, r4.w};
    int   cc[4] = {c4.x, c4.y, c4.z, c4.w};
    float vv[4] = {v4.x, v4.y, v4.z, v4.w};
    #pragma unroll
    for (int j = 0; j < 4; ++j) {
        const int band = rr[j] >> shift;
        const unsigned int e = ((unsigned int)(rr[j] & rmask) << 28)
                             | ((unsigned int)cc[j] << 16)
                             | (unsigned int)f2bf(vv[j]);
        const int pos = atomicAdd(&lcount[band], 1);
        if (pos < PADL_) {
            stage[band][pos] = e;
        } else {
            const int op = atomicAdd(&goc[mat], 1);
            gof[mat * 4096 + op] = make_uint2((unsigned int)band, e);
        }
    }
    __syncthreads();
    unsigned int* seg = bands + ((unsigned int)(mat * 256 + t) * 256 + chunk) * PADL_;
    const uint4* sp = (const uint4*)&stage[t][0];
    *(uint4*)(seg)     = sp[0];
    *(uint4*)(seg + 4) = sp[1];
    *(uint4*)(seg + 8) = sp[2];
    cnt[(mat * 256 + t) * 256 + chunk] = lcount[t];
}

__global__ __launch_bounds__(512) void build_ug_kernel(
    const unsigned int* __restrict__ bands,
    const int* __restrict__ cnt,
    const int* __restrict__ goc, const uint2* __restrict__ gof,
    unsigned short* __restrict__ WUP,
    unsigned short* __restrict__ WGATE) {
    __shared__ float acc[8 * 1024];
    __shared__ int lcnt[256];
    const int b = blockIdx.x;
    const int t = threadIdx.x;
    const int mat = b >> 9;
    const int rem = b & 511;
    const int band = rem >> 1;
    const int hb = rem & 1;
    unsigned short* out = (mat ? WGATE : WUP) + (band * 16 + hb * 8) * 1024;
    const unsigned int rbase = hb * 8;

    for (int k = 0; k < 4; ++k)
        *(float4*)&acc[(k * 512 + t) * 4] = make_float4(0.f, 0.f, 0.f, 0.f);
    if (t < 256) lcnt[t] = cnt[(mat * 256 + band) * 256 + t];
    __syncthreads();

    const int chunk = t & 255;
    const int half = t >> 8;
    const unsigned int* seg = bands + ((unsigned int)(mat * 256 + band) * 256 + chunk) * PADL_;
    const int c = lcnt[chunk];

    if (half == 0) {
        uint4 q[3];
        const uint4* sp = (const uint4*)seg;
        #pragma unroll
        for (int i = 0; i < 3; ++i) q[i] = sp[i];
        const unsigned int* qq = (const unsigned int*)q;
        #pragma unroll
        for (int j = 0; j < PADL_; ++j) {
            const unsigned int e = qq[j];
            const unsigned int r2 = (e >> 28) - rbase;
            if (j < c && r2 < 8u)
                atomicAdd(&acc[r2 * 1024 + ((e >> 16) & 0xFFFu)],
                          __uint_as_float(e << 16));
        }
    } else {
        const int oc = goc[mat] < 4096 ? goc[mat] : 4096;
        for (int i = chunk; i < oc; i += 256) {
            uint2 oe = gof[mat * 4096 + i];
            if ((int)oe.x == band) {
                const unsigned int e = oe.y;
                const unsigned int r2 = (e >> 28) - rbase;
                if (r2 < 8u)
                    atomicAdd(&acc[r2 * 1024 + ((e >> 16) & 0xFFFu)],
                              __uint_as_float(e << 16));
            }
        }
    }
    __syncthreads();

    for (int k = 0; k < 4; ++k) {
        const int cc = (k * 512 + t) * 4;
        ushort4 o;
        o.x = f2bf(acc[cc]);     o.y = f2bf(acc[cc + 1]);
        o.z = f2bf(acc[cc + 2]); o.w = f2bf(acc[cc + 3]);
        *(ushort4*)(out + cc) = o;
    }
}

__global__ __launch_bounds__(256) void fused_upgate_builddown_kernel(
    const unsigned short* __restrict__ xb,
    const unsigned short* __restrict__ wup,
    const unsigned short* __restrict__ wgate,
    const float* __restrict__ up_bias,
    const float* __restrict__ gate_bias,
    unsigned short* __restrict__ hid,
    const unsigned int* __restrict__ bands,
    const int* __restrict__ cnt,
    const int* __restrict__ goc, const uint2* __restrict__ gof,
    unsigned short* __restrict__ WDOWN) {
    __shared__ __align__(16) unsigned short smem_us[9 * 2048];   // 36 KB
    const int b = blockIdx.x;
    const int t = threadIdx.x;

    if (b >= 512) {
        float* acc = (float*)smem_us;
        int*   lcnt = (int*)(smem_us + 16384);
        const int rem = b - 512;
        const int band = rem >> 1;
        const int hb = rem & 1;
        const unsigned int rbase = hb * 2;
        unsigned short* out = WDOWN + (band * 4 + hb * 2) * 4096;

        #pragma unroll
        for (int k = 0; k < 8; ++k)
            *(float4*)&acc[(k * 256 + t) * 4] = make_float4(0.f, 0.f, 0.f, 0.f);
        lcnt[t] = cnt[(2 * 256 + band) * 256 + t];
        __syncthreads();

        const unsigned int* seg = bands + ((unsigned int)(2 * 256 + band) * 256 + t) * PADL_;
        const int c = lcnt[t];
        uint4 q[3];
        const uint4* sp = (const uint4*)seg;
        #pragma unroll
        for (int i = 0; i < 3; ++i) q[i] = sp[i];
        const unsigned int* qq = (const unsigned int*)q;
        #pragma unroll
        for (int j = 0; j < PADL_; ++j) {
            const unsigned int e = qq[j];
            const unsigned int r2 = (e >> 28) - rbase;
            if (j < c && r2 < 2u)
                atomicAdd(&acc[r2 * 4096 + ((e >> 16) & 0xFFFu)],
                          __uint_as_float(e << 16));
        }
        const int oc = goc[2] < 4096 ? goc[2] : 4096;
        for (int i = t; i < oc; i += 256) {
            uint2 oe = gof[2 * 4096 + i];
            if ((int)oe.x == band) {
                const unsigned int e = oe.y;
                const unsigned int r2 = (e >> 28) - rbase;
                if (r2 < 2u)
                    atomicAdd(&acc[r2 * 4096 + ((e >> 16) & 0xFFFu)],
                              __uint_as_float(e << 16));
            }
        }
        __syncthreads();

        #pragma unroll
        for (int k = 0; k < 8; ++k) {
            const int cc = (k * 256 + t) * 4;
            ushort4 o;
            o.x = f2bf(acc[cc]);     o.y = f2bf(acc[cc + 1]);
            o.z = f2bf(acc[cc + 2]); o.w = f2bf(acc[cc + 3]);
            *(ushort4*)(out + cc) = o;
        }
        return;
    }

    unsigned short* sA_  = smem_us;
    unsigned short* sBu_ = smem_us + 3 * 2048;
    unsigned short* sBg_ = smem_us + 6 * 2048;
    const int n0 = (b & 63) * 64;
    const int m0 = (b >> 6) * 64;
    const int w = t >> 6, l = t & 63;
    const int wm = (w >> 1) * 32, wn = (w & 1) * 32;
    const int lr = l & 15, lkq = (l >> 4);

    float4v au[2][2], ag[2][2];
    for (int im = 0; im < 2; ++im)
        for (int in = 0; in < 2; ++in) {
            au[im][in] = float4v{0.f, 0.f, 0.f, 0.f};
            ag[im][in] = float4v{0.f, 0.f, 0.f, 0.f};
        }

    const int srow = t >> 2, scol = (t & 3) * 8;
    const unsigned short* gA  = xb    + (m0 + srow) * DIM_ + scol;
    const unsigned short* gBu = wup   + (n0 + srow) * DIM_ + scol;
    const unsigned short* gBg = wgate + (n0 + srow) * DIM_ + scol;

    STAGE_UG(0, 0);
    STAGE_UG(1, 32);
    int cur = 0;
    for (int k0 = 64; k0 < DIM_; k0 += 32) {
        PIPE_BAR(3);
        const int nn = cur == 0 ? 2 : cur - 1;
        STAGE_UG(nn, k0);
        COMPUTE_UG(cur);
        cur = cur == 2 ? 0 : cur + 1;
    }
    PIPE_BAR(3);
    COMPUTE_UG(cur);
    cur = cur == 2 ? 0 : cur + 1;
    PIPE_BAR(0);
    COMPUTE_UG(cur);

    for (int im = 0; im < 2; ++im) {
        for (int in = 0; in < 2; ++in) {
            const int n = n0 + wn + in * 16 + lr;
            const float ub = up_bias[n], gb = gate_bias[n];
            for (int r = 0; r < 4; ++r) {
                const int m = m0 + wm + im * 16 + lkq * 4 + r;
                const float u = au[im][in][r] + ub;
                const float g = ag[im][in][r] + gb;
                const float h = (u / (1.f + __expf(-u))) * g;
                hid[m * HIDDEN_ + n] = f2bf(h);
            }
        }
    }
}

__global__ __launch_bounds__(256) void gemm_down_kernel(
    const unsigned short* __restrict__ hid,
    const unsigned short* __restrict__ wdown,
    float* __restrict__ out) {
    __shared__ __align__(16) unsigned short sA[3 * 2048];
    __shared__ __align__(16) unsigned short sB[3 * 2048];
    const int t = threadIdx.x;
    const int n0 = blockIdx.x * 64;
    const int m0 = blockIdx.y * 64;
    const int kb0 = blockIdx.z * 512;
    const int w = t >> 6, l = t & 63;
    const int wm = (w >> 1) * 32, wn = (w & 1) * 32;
    const int lr = l & 15, lkq = (l >> 4);

    float4v acc[2][2];
    for (int im = 0; im < 2; ++im)
        for (int in = 0; in < 2; ++in)
            acc[im][in] = float4v{0.f, 0.f, 0.f, 0.f};

    const int srow = t >> 2, scol = (t & 3) * 8;
    const unsigned short* gA = hid   + (m0 + srow) * HIDDEN_ + scol;
    const unsigned short* gB = wdown + (n0 + srow) * HIDDEN_ + scol;

    STAGE_DN(0, kb0);
    STAGE_DN(1, kb0 + 32);
    int cur = 0;
    for (int k0 = kb0 + 64; k0 < kb0 + 512; k0 += 32) {
        PIPE_BAR(2);
        const int nn = cur == 0 ? 2 : cur - 1;
        STAGE_DN(nn, k0);
        COMPUTE_DN(cur);
        cur = cur == 2 ? 0 : cur + 1;
    }
    PIPE_BAR(2);
    COMPUTE_DN(cur);
    cur = cur == 2 ? 0 : cur + 1;
    PIPE_BAR(0);
    COMPUTE_DN(cur);

    for (int im = 0; im < 2; ++im) {
        for (int in = 0; in < 2; ++in) {
            const int n = n0 + wn + in * 16 + lr;
            for (int r = 0; r < 4; ++r) {
                const int m = m0 + wm + im * 16 + lkq * 4 + r;
                atomicAdd(out + m * DIM_ + n, acc[im][in][r]);
            }
        }
    }
}

// ---------------------------------------------------------------- launch
extern "C" void kernel_launch(void* const* d_in, const int* in_sizes, int n_in,
                              void* d_out, int out_size, void* d_ws, size_t ws_size,
                              hipStream_t stream) {
    const float* x         = (const float*)d_in[0];
    const int*   up_row    = (const int*)d_in[1];
    const int*   up_col    = (const int*)d_in[2];
    const float* up_val    = (const float*)d_in[3];
    const float* up_bias   = (const float*)d_in[4];
    const int*   gate_row  = (const int*)d_in[5];
    const int*   gate_col  = (const int*)d_in[6];
    const float* gate_val  = (const float*)d_in[7];
    const float* gate_bias = (const float*)d_in[8];
    const int*   down_row  = (const int*)d_in[9];
    const int*   down_col  = (const int*)d_in[10];
    const float* down_val  = (const float*)d_in[11];
    const float* down_bias = (const float*)d_in[12];
    float* out = (float*)d_out;

    unsigned char* ws = (unsigned char*)d_ws;
    unsigned short* WUP   = (unsigned short*)(ws);
    unsigned short* WGATE = (unsigned short*)(ws + (8u << 20));
    unsigned short* WDOWN = (unsigned short*)(ws + (16u << 20));
    unsigned short* XB    = (unsigned short*)(ws + (24u << 20));
    unsigned short* HID   = (unsigned short*)(ws + (25u << 20));
    unsigned int*   BANDS = (unsigned int*)(ws + (29u << 20));
    int*            CNT   = (int*)(ws + (66u << 20));
    int*            GOC   = (int*)(ws + (67u << 20));
    uint2*          GOF   = (uint2*)(ws + (67u << 20) + 64);

    hipMemsetAsync(GOC, 0, 3 * sizeof(int), stream);

    void* args[] = {
        (void*)&up_row,  (void*)&up_col,  (void*)&up_val,
        (void*)&gate_row,(void*)&gate_col,(void*)&gate_val,
        (void*)&down_row,(void*)&down_col,(void*)&down_val,
        (void*)&x, (void*)&up_bias, (void*)&gate_bias,
        (void*)&WUP, (void*)&WGATE, (void*)&WDOWN, (void*)&XB, (void*)&HID,
        (void*)&BANDS, (void*)&CNT, (void*)&GOC, (void*)&GOF,
        (void*)&down_bias, (void*)&out
    };
    hipError_t rc = hipLaunchCooperativeKernel(
        mega_kernel, dim3(1024), dim3(256), args, 0u, stream);
    if (rc == hipSuccess) return;
    (void)hipGetLastError();   // clear; fall back to the R16 4-kernel path

    bin_prep_kernel<<<1024, 256, 0, stream>>>(
        up_row, up_col, up_val, gate_row, gate_col, gate_val,
        down_row, down_col, down_val, x, down_bias, BANDS, CNT, GOC, GOF, XB, out);

    build_ug_kernel<<<1024, 512, 0, stream>>>(BANDS, CNT, GOC, GOF, WUP, WGATE);

    fused_upgate_builddown_kernel<<<1024, 256, 0, stream>>>(
        XB, WUP, WGATE, up_bias, gate_bias, HID, BANDS, CNT, GOC, GOF, WDOWN);

    gemm_down_kernel<<<dim3(DIM_ / 64, TTOK_ / 64, 8), 256, 0, stream>>>(
        HID, WDOWN, out);
}

// Round 5
// 381.038 us; speedup vs baseline: 2.1661x; 2.1661x over previous
//
#include <hip/hip_runtime.h>
#include <hip/hip_bf16.h>
#include <stdint.h>

// SparseSwiGLU on MI355X: fine-band radix densify -> bf16 weights -> MFMA GEMMs.
// R18 = R16 structure (coop grid.sync REVERTED: measured 743us mega_kernel,
// ~700us of grid.sync stall on gfx950 -> disqualified) + DIAGNOSTIC inflation:
//   - fused upgate GEMM role repeats x8 in-kernel (idempotent HID rewrite)
//   - gemm_down launched x8 (7 into scratch, 8th real)
// Purpose: the 268MB re-poison fills (~44us) occupy all top-5 rocprof slots,
// so per-phase durations have never been observed; 4 GEMM-schedule rewrites
// (R13-R16) all landed 133-139us. Inflation makes the GEMM phases the top
// dispatches: top-5 row ~ 8*t_upgate WITH counters; t_down from dur arithmetic
// (dur ~ 139 + 7*t_ug + 7*t_dn). Decision rule pre-committed in the journal.
// T=512 tokens, DIM=1024, HIDDEN=4096, NNZ=262144 per matrix.
//
// Workspace layout (<= 68 MB):
//   [0,    8MB)  WUP    bf16 [4096][1024]   (B^T, K-contiguous)
//   [8MB, 16MB)  WGATE  bf16 [4096][1024]
//   [16MB,24MB)  WDOWN  bf16 [1024][4096]
//   [24MB,25MB)  XB     bf16 [512][1024]
//   [25MB,29MB)  HID    bf16 [512][4096]
//   [29MB,+9MB)  BANDS  uint[3][256 band][256 chunk][12 slot]  (scratch for
//                        diagnostic down-GEMM launches after build consumes it)
//   [66MB,+768K) CNT    int[3][256][256]
//   [67MB,+12B)  GOC    int[3]              overflow counters
//   [67MB+64,..) GOF    uint2[3][4096]      overflow entries (band, packed)

#define DIM_    1024
#define HIDDEN_ 4096
#define NNZ_    262144
#define TTOK_   512
#define PADL_   12              // 48 B segments; P(X>12|lam=4) ~ 2.7e-4
#define REPS_UG 8               // diagnostic inflation factor (upgate GEMM role)
#define REPS_DN 8               // diagnostic inflation factor (down GEMM launches)

typedef __attribute__((ext_vector_type(8))) short short8;
typedef __attribute__((ext_vector_type(4))) float float4v;

__device__ inline unsigned short f2bf(float f) {
    union { float f; unsigned int u; } c; c.f = f;
    unsigned int u = c.u;
    unsigned int r = u + 0x7fffu + ((u >> 16) & 1u);   // RNE
    return (unsigned short)(r >> 16);
}

__device__ inline void async16(const unsigned short* g, unsigned short* l) {
    __builtin_amdgcn_global_load_lds(
        (const __attribute__((address_space(1))) unsigned int*)g,
        (__attribute__((address_space(3))) unsigned int*)l, 16, 0, 0);
}

// Counted-vmcnt pipeline barrier: wait for all but N outstanding global_load_lds,
// then block barrier. sched_barrier(0) pins code motion across it (rule #18).
#define PIPE_BAR(N)                                                         \
    __builtin_amdgcn_sched_barrier(0);                                      \
    asm volatile("s_waitcnt vmcnt(" #N ") lgkmcnt(0)" ::: "memory");        \
    __builtin_amdgcn_s_barrier();                                           \
    __builtin_amdgcn_sched_barrier(0);

// ---------------------------------------------------------------- bin+prep (R12)
#define XC_ ((TTOK_ * DIM_) / 4)           // 131072 float4 units

__global__ __launch_bounds__(256) void bin_prep_kernel(
    const int* __restrict__ ur, const int* __restrict__ uc, const float* __restrict__ uv,
    const int* __restrict__ gr, const int* __restrict__ gc, const float* __restrict__ gv,
    const int* __restrict__ dr, const int* __restrict__ dc, const float* __restrict__ dv,
    const float* __restrict__ x, const float* __restrict__ down_bias,
    unsigned int* __restrict__ bands, int* __restrict__ cnt,
    int* __restrict__ goc, uint2* __restrict__ gof,
    unsigned short* __restrict__ xb, float* __restrict__ out) {
    const int b = blockIdx.x;
    const int t = threadIdx.x;
    if (b >= 768) {
        const unsigned int u0 = (b - 768) * 1024 + t * 4;
        #pragma unroll
        for (int q = 0; q < 4; ++q) {
            const unsigned int id = u0 + q;
            if (id < XC_) {
                float4 v = ((const float4*)x)[id];
                ushort4 o;
                o.x = f2bf(v.x); o.y = f2bf(v.y); o.z = f2bf(v.z); o.w = f2bf(v.w);
                ((ushort4*)xb)[id] = o;
            } else {
                const unsigned int i = id - XC_;
                float4 v = ((const float4*)x)[i];
                const int d = (i * 4) & (DIM_ - 1);
                const float4 bb = *(const float4*)(down_bias + d);
                float4 o;
                o.x = v.x + bb.x; o.y = v.y + bb.y; o.z = v.z + bb.z; o.w = v.w + bb.w;
                ((float4*)out)[i] = o;
            }
        }
        return;
    }
    __shared__ unsigned int stage[256][PADL_];   // 12 KB
    __shared__ int lcount[256];
    const int mat = b >> 8;          // 0 up, 1 gate, 2 down
    const int chunk = b & 255;
    const int*   rs = (mat == 0) ? ur : (mat == 1) ? gr : dr;
    const int*   cs = (mat == 0) ? uc : (mat == 1) ? gc : dc;
    const float* vs = (mat == 0) ? uv : (mat == 1) ? gv : dv;
    const int shift = (mat == 2) ? 2 : 4;   // rows/band: 4 (down), 16 (up/gate)
    const int rmask = (mat == 2) ? 3 : 15;
    lcount[t] = 0;
    __syncthreads();

    const int base = chunk * 1024 + t * 4;
    int4   r4 = *(const int4*)(rs + base);
    int4   c4 = *(const int4*)(cs + base);
    float4 v4 = *(const float4*)(vs + base);
    int   rr[4] = {r4.x, r4.y, r4.z, r4.w};
    int   cc[4] = {c4.x, c4.y, c4.z, c4.w};
    float vv[4] = {v4.x, v4.y, v4.z, v4.w};
    #pragma unroll
    for (int j = 0; j < 4; ++j) {
        const int band = rr[j] >> shift;
        const unsigned int e = ((unsigned int)(rr[j] & rmask) << 28)
                             | ((unsigned int)cc[j] << 16)
                             | (unsigned int)f2bf(vv[j]);
        const int pos = atomicAdd(&lcount[band], 1);
        if (pos < PADL_) {
            stage[band][pos] = e;
        } else {                       // ~53 grid-wide: global overflow list
            const int op = atomicAdd(&goc[mat], 1);
            gof[mat * 4096 + op] = make_uint2((unsigned int)band, e);
        }
    }
    __syncthreads();
    // coalesced writeout: thread t streams band t's 48B segment (3 dwordx4)
    unsigned int* seg = bands + ((unsigned int)(mat * 256 + t) * 256 + chunk) * PADL_;
    const uint4* sp = (const uint4*)&stage[t][0];
    *(uint4*)(seg)     = sp[0];
    *(uint4*)(seg + 4) = sp[1];
    *(uint4*)(seg + 8) = sp[2];
    cnt[(mat * 256 + t) * 256 + chunk] = lcount[t];
}

// ---------------------------------------------------------------- build up/gate
__global__ __launch_bounds__(512) void build_ug_kernel(
    const unsigned int* __restrict__ bands,
    const int* __restrict__ cnt,
    const int* __restrict__ goc, const uint2* __restrict__ gof,
    unsigned short* __restrict__ WUP,
    unsigned short* __restrict__ WGATE) {
    __shared__ float acc[8 * 1024];
    __shared__ int lcnt[256];
    const int b = blockIdx.x;
    const int t = threadIdx.x;
    const int mat = b >> 9;            // 0 up, 1 gate
    const int rem = b & 511;
    const int band = rem >> 1;
    const int hb = rem & 1;            // row half within the band
    unsigned short* out = (mat ? WGATE : WUP) + (band * 16 + hb * 8) * 1024;
    const unsigned int rbase = hb * 8;

    for (int k = 0; k < 4; ++k)
        *(float4*)&acc[(k * 512 + t) * 4] = make_float4(0.f, 0.f, 0.f, 0.f);
    if (t < 256) lcnt[t] = cnt[(mat * 256 + band) * 256 + t];
    __syncthreads();

    const int chunk = t & 255;
    const int half = t >> 8;
    const unsigned int* seg = bands + ((unsigned int)(mat * 256 + band) * 256 + chunk) * PADL_;
    const int c = lcnt[chunk];

    if (half == 0) {
        uint4 q[3];
        const uint4* sp = (const uint4*)seg;
        #pragma unroll
        for (int i = 0; i < 3; ++i) q[i] = sp[i];
        const unsigned int* qq = (const unsigned int*)q;
        #pragma unroll
        for (int j = 0; j < PADL_; ++j) {
            const unsigned int e = qq[j];
            const unsigned int r2 = (e >> 28) - rbase;   // unsigned wrap filter
            if (j < c && r2 < 8u)
                atomicAdd(&acc[r2 * 1024 + ((e >> 16) & 0xFFFu)],
                          __uint_as_float(e << 16));
        }
    } else {
        const int oc = goc[mat] < 4096 ? goc[mat] : 4096;
        for (int i = chunk; i < oc; i += 256) {
            uint2 oe = gof[mat * 4096 + i];
            if ((int)oe.x == band) {
                const unsigned int e = oe.y;
                const unsigned int r2 = (e >> 28) - rbase;
                if (r2 < 8u)
                    atomicAdd(&acc[r2 * 1024 + ((e >> 16) & 0xFFFu)],
                              __uint_as_float(e << 16));
            }
        }
    }
    __syncthreads();

    for (int k = 0; k < 4; ++k) {
        const int cc = (k * 512 + t) * 4;
        ushort4 o;
        o.x = f2bf(acc[cc]);     o.y = f2bf(acc[cc + 1]);
        o.z = f2bf(acc[cc + 2]); o.w = f2bf(acc[cc + 3]);
        *(ushort4*)(out + cc) = o;
    }
}

// ------------------------------------------------ fused upgate GEMM + build_down
// Blocks [0,512): up+gate GEMM x REPS_UG (diagnostic, idempotent).
// Blocks [512,1024): build WDOWN (runs once).
#define STAGE_UG(buf, k0)                                      \
    async16(gA + (k0),  sA_  + (buf) * 2048 + t * 8);          \
    async16(gBu + (k0), sBu_ + (buf) * 2048 + t * 8);          \
    async16(gBg + (k0), sBg_ + (buf) * 2048 + t * 8);

#define COMPUTE_UG(buf)                                                        \
    {                                                                          \
        const int kb = (buf) * 2048 + lkq * 8;                                 \
        short8 a[2], bu[2], bg[2];                                             \
        _Pragma("unroll")                                                      \
        for (int im = 0; im < 2; ++im)                                         \
            a[im] = *(const short8*)&sA_[kb + (wm + im * 16 + lr) * 32];       \
        _Pragma("unroll")                                                      \
        for (int in = 0; in < 2; ++in) {                                       \
            bu[in] = *(const short8*)&sBu_[kb + (wn + in * 16 + lr) * 32];     \
            bg[in] = *(const short8*)&sBg_[kb + (wn + in * 16 + lr) * 32];     \
        }                                                                      \
        _Pragma("unroll")                                                      \
        for (int im = 0; im < 2; ++im)                                         \
            _Pragma("unroll")                                                  \
            for (int in = 0; in < 2; ++in) {                                   \
                au[im][in] = __builtin_amdgcn_mfma_f32_16x16x32_bf16(          \
                    a[im], bu[in], au[im][in], 0, 0, 0);                       \
                ag[im][in] = __builtin_amdgcn_mfma_f32_16x16x32_bf16(          \
                    a[im], bg[in], ag[im][in], 0, 0, 0);                       \
            }                                                                  \
    }

__global__ __launch_bounds__(256) void fused_upgate_builddown_kernel(
    const unsigned short* __restrict__ xb,      // [512][1024]
    const unsigned short* __restrict__ wup,     // [4096][1024]
    const unsigned short* __restrict__ wgate,   // [4096][1024]
    const float* __restrict__ up_bias,
    const float* __restrict__ gate_bias,
    unsigned short* __restrict__ hid,           // [512][4096]
    const unsigned int* __restrict__ bands,
    const int* __restrict__ cnt,
    const int* __restrict__ goc, const uint2* __restrict__ gof,
    unsigned short* __restrict__ WDOWN) {       // [1024][4096]
    __shared__ __align__(16) unsigned short smem_us[9 * 2048];   // 36 KB
    const int b = blockIdx.x;
    const int t = threadIdx.x;

    if (b >= 512) {
        // ---- build WDOWN: band half (2 rows of 4096); 32KB acc + 1KB lcnt ----
        float* acc = (float*)smem_us;                    // 32 KB
        int*   lcnt = (int*)(smem_us + 16384);           // 1 KB
        const int rem = b - 512;
        const int band = rem >> 1;
        const int hb = rem & 1;
        const unsigned int rbase = hb * 2;
        unsigned short* out = WDOWN + (band * 4 + hb * 2) * 4096;

        #pragma unroll
        for (int k = 0; k < 8; ++k)
            *(float4*)&acc[(k * 256 + t) * 4] = make_float4(0.f, 0.f, 0.f, 0.f);
        lcnt[t] = cnt[(2 * 256 + band) * 256 + t];
        __syncthreads();

        const unsigned int* seg = bands + ((unsigned int)(2 * 256 + band) * 256 + t) * PADL_;
        const int c = lcnt[t];
        uint4 q[3];
        const uint4* sp = (const uint4*)seg;
        #pragma unroll
        for (int i = 0; i < 3; ++i) q[i] = sp[i];
        const unsigned int* qq = (const unsigned int*)q;
        #pragma unroll
        for (int j = 0; j < PADL_; ++j) {
            const unsigned int e = qq[j];
            const unsigned int r2 = (e >> 28) - rbase;   // unsigned wrap filter
            if (j < c && r2 < 2u)
                atomicAdd(&acc[r2 * 4096 + ((e >> 16) & 0xFFFu)],
                          __uint_as_float(e << 16));
        }
        const int oc = goc[2] < 4096 ? goc[2] : 4096;
        for (int i = t; i < oc; i += 256) {
            uint2 oe = gof[2 * 4096 + i];
            if ((int)oe.x == band) {
                const unsigned int e = oe.y;
                const unsigned int r2 = (e >> 28) - rbase;
                if (r2 < 2u)
                    atomicAdd(&acc[r2 * 4096 + ((e >> 16) & 0xFFFu)],
                              __uint_as_float(e << 16));
            }
        }
        __syncthreads();

        #pragma unroll
        for (int k = 0; k < 8; ++k) {
            const int cc = (k * 256 + t) * 4;
            ushort4 o;
            o.x = f2bf(acc[cc]);     o.y = f2bf(acc[cc + 1]);
            o.z = f2bf(acc[cc + 2]); o.w = f2bf(acc[cc + 3]);
            *(ushort4*)(out + cc) = o;
        }
        return;
    }

    // ---- up+gate GEMM tile: 64Mx64N, BK=32, 3-deep; repeated REPS_UG x ----
    unsigned short* sA_  = smem_us;                 // [3][2048]
    unsigned short* sBu_ = smem_us + 3 * 2048;
    unsigned short* sBg_ = smem_us + 6 * 2048;
    const int n0 = (b & 63) * 64;
    const int m0 = (b >> 6) * 64;
    const int w = t >> 6, l = t & 63;
    const int wm = (w >> 1) * 32, wn = (w & 1) * 32;
    const int lr = l & 15, lkq = (l >> 4);

    const int srow = t >> 2, scol = (t & 3) * 8;
    const unsigned short* gA  = xb    + (m0 + srow) * DIM_ + scol;
    const unsigned short* gBu = wup   + (n0 + srow) * DIM_ + scol;
    const unsigned short* gBg = wgate + (n0 + srow) * DIM_ + scol;

    #pragma unroll 1
    for (int irep = 0; irep < REPS_UG; ++irep) {
        float4v au[2][2], ag[2][2];
        for (int im = 0; im < 2; ++im)
            for (int in = 0; in < 2; ++in) {
                au[im][in] = float4v{0.f, 0.f, 0.f, 0.f};
                ag[im][in] = float4v{0.f, 0.f, 0.f, 0.f};
            }

        STAGE_UG(0, 0);
        STAGE_UG(1, 32);
        int cur = 0;
        for (int k0 = 64; k0 < DIM_; k0 += 32) {      // 30 iterations
            PIPE_BAR(3);
            const int nn = cur == 0 ? 2 : cur - 1;    // (cur+2)%3 — freed buffer
            STAGE_UG(nn, k0);
            COMPUTE_UG(cur);
            cur = cur == 2 ? 0 : cur + 1;
        }
        PIPE_BAR(3);
        COMPUTE_UG(cur);                 // step 30
        cur = cur == 2 ? 0 : cur + 1;
        PIPE_BAR(0);
        COMPUTE_UG(cur);                 // step 31

        for (int im = 0; im < 2; ++im) {
            for (int in = 0; in < 2; ++in) {
                const int n = n0 + wn + in * 16 + lr;
                const float ub = up_bias[n], gb = gate_bias[n];
                for (int r = 0; r < 4; ++r) {
                    const int m = m0 + wm + im * 16 + lkq * 4 + r;
                    const float u = au[im][in][r] + ub;
                    const float g = ag[im][in][r] + gb;
                    const float h = (u / (1.f + __expf(-u))) * g;
                    hid[m * HIDDEN_ + n] = f2bf(h);
                }
            }
        }
        __syncthreads();   // all reps identical; keep buffers quiesced between reps
    }
}

// ---------------------------------------------------------------- down GEMM
// BK=32, 3-deep (24KB), split-K=8 (grid 1024 = 4/CU). atomicAdd epilogue onto
// the given target (scratch for diagnostic reps, real out for the last).
#define STAGE_DN(buf, k0)                                      \
    async16(gA + (k0), sA + (buf) * 2048 + t * 8);             \
    async16(gB + (k0), sB + (buf) * 2048 + t * 8);

#define COMPUTE_DN(buf)                                                        \
    {                                                                          \
        const int kb = (buf) * 2048 + lkq * 8;                                 \
        short8 a[2], b2[2];                                                    \
        _Pragma("unroll")                                                      \
        for (int im = 0; im < 2; ++im)                                         \
            a[im] = *(const short8*)&sA[kb + (wm + im * 16 + lr) * 32];        \
        _Pragma("unroll")                                                      \
        for (int in = 0; in < 2; ++in)                                         \
            b2[in] = *(const short8*)&sB[kb + (wn + in * 16 + lr) * 32];       \
        _Pragma("unroll")                                                      \
        for (int im = 0; im < 2; ++im)                                         \
            _Pragma("unroll")                                                  \
            for (int in = 0; in < 2; ++in)                                     \
                acc[im][in] = __builtin_amdgcn_mfma_f32_16x16x32_bf16(         \
                    a[im], b2[in], acc[im][in], 0, 0, 0);                      \
    }

__global__ __launch_bounds__(256) void gemm_down_kernel(
    const unsigned short* __restrict__ hid,     // [512][4096]
    const unsigned short* __restrict__ wdown,   // [1024][4096]
    float* __restrict__ out) {                  // [512][1024] (or scratch)
    __shared__ __align__(16) unsigned short sA[3 * 2048];   // 12 KB
    __shared__ __align__(16) unsigned short sB[3 * 2048];   // 12 KB
    const int t = threadIdx.x;
    const int n0 = blockIdx.x * 64;
    const int m0 = blockIdx.y * 64;
    const int kb0 = blockIdx.z * 512;           // split-K = 8
    const int w = t >> 6, l = t & 63;
    const int wm = (w >> 1) * 32, wn = (w & 1) * 32;
    const int lr = l & 15, lkq = (l >> 4);

    float4v acc[2][2];
    for (int im = 0; im < 2; ++im)
        for (int in = 0; in < 2; ++in)
            acc[im][in] = float4v{0.f, 0.f, 0.f, 0.f};

    const int srow = t >> 2, scol = (t & 3) * 8;
    const unsigned short* gA = hid   + (m0 + srow) * HIDDEN_ + scol;
    const unsigned short* gB = wdown + (n0 + srow) * HIDDEN_ + scol;

    STAGE_DN(0, kb0);
    STAGE_DN(1, kb0 + 32);
    int cur = 0;
    for (int k0 = kb0 + 64; k0 < kb0 + 512; k0 += 32) {   // 14 iterations
        PIPE_BAR(2);
        const int nn = cur == 0 ? 2 : cur - 1;
        STAGE_DN(nn, k0);
        COMPUTE_DN(cur);
        cur = cur == 2 ? 0 : cur + 1;
    }
    PIPE_BAR(2);
    COMPUTE_DN(cur);                 // step 14
    cur = cur == 2 ? 0 : cur + 1;
    PIPE_BAR(0);
    COMPUTE_DN(cur);                 // step 15

    for (int im = 0; im < 2; ++im) {
        for (int in = 0; in < 2; ++in) {
            const int n = n0 + wn + in * 16 + lr;
            for (int r = 0; r < 4; ++r) {
                const int m = m0 + wm + im * 16 + lkq * 4 + r;
                atomicAdd(out + m * DIM_ + n, acc[im][in][r]);
            }
        }
    }
}

// ---------------------------------------------------------------- launch
extern "C" void kernel_launch(void* const* d_in, const int* in_sizes, int n_in,
                              void* d_out, int out_size, void* d_ws, size_t ws_size,
                              hipStream_t stream) {
    const float* x         = (const float*)d_in[0];
    const int*   up_row    = (const int*)d_in[1];
    const int*   up_col    = (const int*)d_in[2];
    const float* up_val    = (const float*)d_in[3];
    const float* up_bias   = (const float*)d_in[4];
    const int*   gate_row  = (const int*)d_in[5];
    const int*   gate_col  = (const int*)d_in[6];
    const float* gate_val  = (const float*)d_in[7];
    const float* gate_bias = (const float*)d_in[8];
    const int*   down_row  = (const int*)d_in[9];
    const int*   down_col  = (const int*)d_in[10];
    const float* down_val  = (const float*)d_in[11];
    const float* down_bias = (const float*)d_in[12];
    float* out = (float*)d_out;

    unsigned char* ws = (unsigned char*)d_ws;
    unsigned short* WUP   = (unsigned short*)(ws);
    unsigned short* WGATE = (unsigned short*)(ws + (8u << 20));
    unsigned short* WDOWN = (unsigned short*)(ws + (16u << 20));
    unsigned short* XB    = (unsigned short*)(ws + (24u << 20));
    unsigned short* HID   = (unsigned short*)(ws + (25u << 20));
    unsigned int*   BANDS = (unsigned int*)(ws + (29u << 20));
    int*            CNT   = (int*)(ws + (66u << 20));
    int*            GOC   = (int*)(ws + (67u << 20));
    uint2*          GOF   = (uint2*)(ws + (67u << 20) + 64);
    // diagnostic scratch for dummy down-GEMM launches: reuse BANDS (dead by then)
    float*          DSCR  = (float*)(ws + (29u << 20));

    hipMemsetAsync(GOC, 0, 3 * sizeof(int), stream);

    bin_prep_kernel<<<1024, 256, 0, stream>>>(
        up_row, up_col, up_val, gate_row, gate_col, gate_val,
        down_row, down_col, down_val, x, down_bias, BANDS, CNT, GOC, GOF, XB, out);

    build_ug_kernel<<<1024, 512, 0, stream>>>(BANDS, CNT, GOC, GOF, WUP, WGATE);

    fused_upgate_builddown_kernel<<<1024, 256, 0, stream>>>(
        XB, WUP, WGATE, up_bias, gate_bias, HID, BANDS, CNT, GOC, GOF, WDOWN);

    for (int r = 0; r < REPS_DN; ++r)
        gemm_down_kernel<<<dim3(DIM_ / 64, TTOK_ / 64, 8), 256, 0, stream>>>(
            HID, WDOWN, (r == REPS_DN - 1) ? out : DSCR);
}

// Round 6
// 134.180 us; speedup vs baseline: 6.1511x; 2.8397x over previous
//
#include <hip/hip_runtime.h>
#include <hip/hip_bf16.h>
#include <stdint.h>

// SparseSwiGLU on MI355X: fine-band radix densify -> bf16 weights -> MFMA GEMMs.
// R19 = R16 structure with the R18 diagnostic reverted, plus two cuts driven
// by the R18 measurements (t_ug~15us, t_dn~20us, ~82us fixed harness window):
//  (1) down GEMM split-K 8->4: 512 blocks, 2.1M device atomics (was 4.2M) --
//      the atomic epilogue, not the K-loop, dominated t_dn.
//  (2) memset graph node deleted: overflow entries go to deterministic
//      per-(mat,chunk) slots with an LDS-local counter; per-chunk counts are
//      written unconditionally by bin -> no pre-zeroed global state. 4 nodes.
// T=512 tokens, DIM=1024, HIDDEN=4096, NNZ=262144 per matrix.
//
// Workspace layout (<= 68 MB):
//   [0,    8MB)  WUP    bf16 [4096][1024]   (B^T, K-contiguous)
//   [8MB, 16MB)  WGATE  bf16 [4096][1024]
//   [16MB,24MB)  WDOWN  bf16 [1024][4096]
//   [24MB,25MB)  XB     bf16 [512][1024]
//   [25MB,29MB)  HID    bf16 [512][4096]
//   [29MB,+9MB)  BANDS  uint[3][256 band][256 chunk][12 slot]
//   [66MB,+768K) CNT    int[3][256][256]
//   [67MB,+3K)   OCNT   int[3][256]          per-chunk overflow counts
//   [67MB+4K,..) GOF    uint2[3][256][16]    per-chunk overflow slots (96KB)

#define DIM_    1024
#define HIDDEN_ 4096
#define NNZ_    262144
#define TTOK_   512
#define PADL_   12              // 48 B segments; P(X>12|lam=4) ~ 2.7e-4
#define OSLOTS_ 16              // overflow slots per (mat,chunk); E[ovf] ~ 0.09

typedef __attribute__((ext_vector_type(8))) short short8;
typedef __attribute__((ext_vector_type(4))) float float4v;

__device__ inline unsigned short f2bf(float f) {
    union { float f; unsigned int u; } c; c.f = f;
    unsigned int u = c.u;
    unsigned int r = u + 0x7fffu + ((u >> 16) & 1u);   // RNE
    return (unsigned short)(r >> 16);
}

__device__ inline void async16(const unsigned short* g, unsigned short* l) {
    __builtin_amdgcn_global_load_lds(
        (const __attribute__((address_space(1))) unsigned int*)g,
        (__attribute__((address_space(3))) unsigned int*)l, 16, 0, 0);
}

// Counted-vmcnt pipeline barrier: wait for all but N outstanding global_load_lds,
// then block barrier. sched_barrier(0) pins code motion across it (rule #18).
#define PIPE_BAR(N)                                                         \
    __builtin_amdgcn_sched_barrier(0);                                      \
    asm volatile("s_waitcnt vmcnt(" #N ") lgkmcnt(0)" ::: "memory");        \
    __builtin_amdgcn_s_barrier();                                           \
    __builtin_amdgcn_sched_barrier(0);

// ---------------------------------------------------------------- bin+prep
// Blocks [0,768): bin — block = (mat, chunk of 1024 nnz), 256 bands/mat
//   (16 rows up/gate, 4 down). Entries staged in LDS stage[256][12], then
//   streamed out as 48B bursts. Overflow -> per-chunk slots (no global ctr).
// Blocks [768,1024): prep — x->bf16 and out = x + down_bias (4 float4/thr).
#define XC_ ((TTOK_ * DIM_) / 4)           // 131072 float4 units

__global__ __launch_bounds__(256) void bin_prep_kernel(
    const int* __restrict__ ur, const int* __restrict__ uc, const float* __restrict__ uv,
    const int* __restrict__ gr, const int* __restrict__ gc, const float* __restrict__ gv,
    const int* __restrict__ dr, const int* __restrict__ dc, const float* __restrict__ dv,
    const float* __restrict__ x, const float* __restrict__ down_bias,
    unsigned int* __restrict__ bands, int* __restrict__ cnt,
    int* __restrict__ ocnt, uint2* __restrict__ gof,
    unsigned short* __restrict__ xb, float* __restrict__ out) {
    const int b = blockIdx.x;
    const int t = threadIdx.x;
    if (b >= 768) {
        const unsigned int u0 = (b - 768) * 1024 + t * 4;
        #pragma unroll
        for (int q = 0; q < 4; ++q) {
            const unsigned int id = u0 + q;
            if (id < XC_) {
                float4 v = ((const float4*)x)[id];
                ushort4 o;
                o.x = f2bf(v.x); o.y = f2bf(v.y); o.z = f2bf(v.z); o.w = f2bf(v.w);
                ((ushort4*)xb)[id] = o;
            } else {
                const unsigned int i = id - XC_;
                float4 v = ((const float4*)x)[i];
                const int d = (i * 4) & (DIM_ - 1);
                const float4 bb = *(const float4*)(down_bias + d);
                float4 o;
                o.x = v.x + bb.x; o.y = v.y + bb.y; o.z = v.z + bb.z; o.w = v.w + bb.w;
                ((float4*)out)[i] = o;
            }
        }
        return;
    }
    __shared__ unsigned int stage[256][PADL_];   // 12 KB
    __shared__ int lcount[256];
    __shared__ int ocount;
    const int mat = b >> 8;          // 0 up, 1 gate, 2 down
    const int chunk = b & 255;
    const int*   rs = (mat == 0) ? ur : (mat == 1) ? gr : dr;
    const int*   cs = (mat == 0) ? uc : (mat == 1) ? gc : dc;
    const float* vs = (mat == 0) ? uv : (mat == 1) ? gv : dv;
    const int shift = (mat == 2) ? 2 : 4;   // rows/band: 4 (down), 16 (up/gate)
    const int rmask = (mat == 2) ? 3 : 15;
    lcount[t] = 0;
    if (t == 0) ocount = 0;
    __syncthreads();

    const int base = chunk * 1024 + t * 4;
    int4   r4 = *(const int4*)(rs + base);
    int4   c4 = *(const int4*)(cs + base);
    float4 v4 = *(const float4*)(vs + base);
    int   rr[4] = {r4.x, r4.y, r4.z, r4.w};
    int   cc[4] = {c4.x, c4.y, c4.z, c4.w};
    float vv[4] = {v4.x, v4.y, v4.z, v4.w};
    #pragma unroll
    for (int j = 0; j < 4; ++j) {
        const int band = rr[j] >> shift;
        const unsigned int e = ((unsigned int)(rr[j] & rmask) << 28)
                             | ((unsigned int)cc[j] << 16)
                             | (unsigned int)f2bf(vv[j]);
        const int pos = atomicAdd(&lcount[band], 1);
        if (pos < PADL_) {
            stage[band][pos] = e;
        } else {                       // rare (~53 grid-wide): per-chunk slots
            const int op = atomicAdd(&ocount, 1);
            if (op < OSLOTS_)
                gof[(mat * 256 + chunk) * OSLOTS_ + op] =
                    make_uint2((unsigned int)band, e);
        }
    }
    __syncthreads();
    // coalesced writeout: thread t streams band t's 48B segment (3 dwordx4)
    unsigned int* seg = bands + ((unsigned int)(mat * 256 + t) * 256 + chunk) * PADL_;
    const uint4* sp = (const uint4*)&stage[t][0];
    *(uint4*)(seg)     = sp[0];
    *(uint4*)(seg + 4) = sp[1];
    *(uint4*)(seg + 8) = sp[2];
    cnt[(mat * 256 + t) * 256 + chunk] = lcount[t];
    if (t == 0)
        ocnt[mat * 256 + chunk] = ocount < OSLOTS_ ? ocount : OSLOTS_;
}

// ---------------------------------------------------------------- build up/gate
// TWO blocks per band, each owning 8 rows; 32KB fp32 LDS + 1KB lcnt -> 4/CU.
// Half 0 threads: slot scan; half 1 threads: per-chunk overflow slots.
__global__ __launch_bounds__(512) void build_ug_kernel(
    const unsigned int* __restrict__ bands,
    const int* __restrict__ cnt,
    const int* __restrict__ ocnt, const uint2* __restrict__ gof,
    unsigned short* __restrict__ WUP,
    unsigned short* __restrict__ WGATE) {
    __shared__ float acc[8 * 1024];
    __shared__ int lcnt[256];
    const int b = blockIdx.x;
    const int t = threadIdx.x;
    const int mat = b >> 9;            // 0 up, 1 gate
    const int rem = b & 511;
    const int band = rem >> 1;
    const int hb = rem & 1;            // row half within the band
    unsigned short* out = (mat ? WGATE : WUP) + (band * 16 + hb * 8) * 1024;
    const unsigned int rbase = hb * 8;

    for (int k = 0; k < 4; ++k)
        *(float4*)&acc[(k * 512 + t) * 4] = make_float4(0.f, 0.f, 0.f, 0.f);
    if (t < 256) lcnt[t] = cnt[(mat * 256 + band) * 256 + t];
    __syncthreads();

    const int chunk = t & 255;
    const int half = t >> 8;
    const unsigned int* seg = bands + ((unsigned int)(mat * 256 + band) * 256 + chunk) * PADL_;
    const int c = lcnt[chunk];

    if (half == 0) {
        uint4 q[3];
        const uint4* sp = (const uint4*)seg;
        #pragma unroll
        for (int i = 0; i < 3; ++i) q[i] = sp[i];
        const unsigned int* qq = (const unsigned int*)q;
        #pragma unroll
        for (int j = 0; j < PADL_; ++j) {
            const unsigned int e = qq[j];
            const unsigned int r2 = (e >> 28) - rbase;   // unsigned wrap filter
            if (j < c && r2 < 8u)
                atomicAdd(&acc[r2 * 1024 + ((e >> 16) & 0xFFFu)],
                          __uint_as_float(e << 16));
        }
    } else {
        // per-chunk overflow slots (written unconditionally by bin)
        const int oc = ocnt[mat * 256 + chunk];
        const uint2* og = gof + (mat * 256 + chunk) * OSLOTS_;
        for (int i = 0; i < oc; ++i) {
            uint2 oe = og[i];
            if ((int)oe.x == band) {
                const unsigned int e = oe.y;
                const unsigned int r2 = (e >> 28) - rbase;
                if (r2 < 8u)
                    atomicAdd(&acc[r2 * 1024 + ((e >> 16) & 0xFFFu)],
                              __uint_as_float(e << 16));
            }
        }
    }
    __syncthreads();

    for (int k = 0; k < 4; ++k) {
        const int cc = (k * 512 + t) * 4;
        ushort4 o;
        o.x = f2bf(acc[cc]);     o.y = f2bf(acc[cc + 1]);
        o.z = f2bf(acc[cc + 2]); o.w = f2bf(acc[cc + 3]);
        *(ushort4*)(out + cc) = o;
    }
}

// ------------------------------------------------ fused upgate GEMM + build_down
// Blocks [0,512):   up+gate GEMM, tile 64Mx64N, BK=32, 3-deep pipeline (36KB),
//                   vmcnt(3) one-barrier steps.
// Blocks [512,1024): build WDOWN — 2 rows per block, 256 threads, 33KB LDS.
// Both fit 4 blocks/CU -> the 1024 blocks co-schedule.
#define STAGE_UG(buf, k0)                                      \
    async16(gA + (k0),  sA_  + (buf) * 2048 + t * 8);          \
    async16(gBu + (k0), sBu_ + (buf) * 2048 + t * 8);          \
    async16(gBg + (k0), sBg_ + (buf) * 2048 + t * 8);

#define COMPUTE_UG(buf)                                                        \
    {                                                                          \
        const int kb = (buf) * 2048 + lkq * 8;                                 \
        short8 a[2], bu[2], bg[2];                                             \
        _Pragma("unroll")                                                      \
        for (int im = 0; im < 2; ++im)                                         \
            a[im] = *(const short8*)&sA_[kb + (wm + im * 16 + lr) * 32];       \
        _Pragma("unroll")                                                      \
        for (int in = 0; in < 2; ++in) {                                       \
            bu[in] = *(const short8*)&sBu_[kb + (wn + in * 16 + lr) * 32];     \
            bg[in] = *(const short8*)&sBg_[kb + (wn + in * 16 + lr) * 32];     \
        }                                                                      \
        _Pragma("unroll")                                                      \
        for (int im = 0; im < 2; ++im)                                         \
            _Pragma("unroll")                                                  \
            for (int in = 0; in < 2; ++in) {                                   \
                au[im][in] = __builtin_amdgcn_mfma_f32_16x16x32_bf16(          \
                    a[im], bu[in], au[im][in], 0, 0, 0);                       \
                ag[im][in] = __builtin_amdgcn_mfma_f32_16x16x32_bf16(          \
                    a[im], bg[in], ag[im][in], 0, 0, 0);                       \
            }                                                                  \
    }

__global__ __launch_bounds__(256) void fused_upgate_builddown_kernel(
    const unsigned short* __restrict__ xb,      // [512][1024]
    const unsigned short* __restrict__ wup,     // [4096][1024]
    const unsigned short* __restrict__ wgate,   // [4096][1024]
    const float* __restrict__ up_bias,
    const float* __restrict__ gate_bias,
    unsigned short* __restrict__ hid,           // [512][4096]
    const unsigned int* __restrict__ bands,
    const int* __restrict__ cnt,
    const int* __restrict__ ocnt, const uint2* __restrict__ gof,
    unsigned short* __restrict__ WDOWN) {       // [1024][4096]
    __shared__ __align__(16) unsigned short smem_us[9 * 2048];   // 36 KB
    const int b = blockIdx.x;
    const int t = threadIdx.x;

    if (b >= 512) {
        // ---- build WDOWN: band half (2 rows of 4096); 32KB acc + 1KB lcnt ----
        float* acc = (float*)smem_us;                    // 32 KB
        int*   lcnt = (int*)(smem_us + 16384);           // 1 KB
        const int rem = b - 512;
        const int band = rem >> 1;
        const int hb = rem & 1;
        const unsigned int rbase = hb * 2;
        unsigned short* out = WDOWN + (band * 4 + hb * 2) * 4096;

        #pragma unroll
        for (int k = 0; k < 8; ++k)
            *(float4*)&acc[(k * 256 + t) * 4] = make_float4(0.f, 0.f, 0.f, 0.f);
        lcnt[t] = cnt[(2 * 256 + band) * 256 + t];
        __syncthreads();

        const unsigned int* seg = bands + ((unsigned int)(2 * 256 + band) * 256 + t) * PADL_;
        const int c = lcnt[t];
        uint4 q[3];
        const uint4* sp = (const uint4*)seg;
        #pragma unroll
        for (int i = 0; i < 3; ++i) q[i] = sp[i];
        const unsigned int* qq = (const unsigned int*)q;
        #pragma unroll
        for (int j = 0; j < PADL_; ++j) {
            const unsigned int e = qq[j];
            const unsigned int r2 = (e >> 28) - rbase;   // unsigned wrap filter
            if (j < c && r2 < 2u)
                atomicAdd(&acc[r2 * 4096 + ((e >> 16) & 0xFFFu)],
                          __uint_as_float(e << 16));
        }
        // per-chunk overflow slots: thread t scans chunk t
        const int oc = ocnt[2 * 256 + t];
        const uint2* og = gof + (2 * 256 + t) * OSLOTS_;
        for (int i = 0; i < oc; ++i) {
            uint2 oe = og[i];
            if ((int)oe.x == band) {
                const unsigned int e = oe.y;
                const unsigned int r2 = (e >> 28) - rbase;
                if (r2 < 2u)
                    atomicAdd(&acc[r2 * 4096 + ((e >> 16) & 0xFFFu)],
                              __uint_as_float(e << 16));
            }
        }
        __syncthreads();

        #pragma unroll
        for (int k = 0; k < 8; ++k) {
            const int cc = (k * 256 + t) * 4;
            ushort4 o;
            o.x = f2bf(acc[cc]);     o.y = f2bf(acc[cc + 1]);
            o.z = f2bf(acc[cc + 2]); o.w = f2bf(acc[cc + 3]);
            *(ushort4*)(out + cc) = o;
        }
        return;
    }

    // ---- up+gate GEMM tile: 64Mx64N, BK=32, 3-deep (3 x 3 x 4KB) ----
    unsigned short* sA_  = smem_us;                 // [3][2048]
    unsigned short* sBu_ = smem_us + 3 * 2048;
    unsigned short* sBg_ = smem_us + 6 * 2048;
    const int n0 = (b & 63) * 64;
    const int m0 = (b >> 6) * 64;
    const int w = t >> 6, l = t & 63;
    const int wm = (w >> 1) * 32, wn = (w & 1) * 32;
    const int lr = l & 15, lkq = (l >> 4);

    float4v au[2][2], ag[2][2];
    for (int im = 0; im < 2; ++im)
        for (int in = 0; in < 2; ++in) {
            au[im][in] = float4v{0.f, 0.f, 0.f, 0.f};
            ag[im][in] = float4v{0.f, 0.f, 0.f, 0.f};
        }

    const int srow = t >> 2, scol = (t & 3) * 8;
    const unsigned short* gA  = xb    + (m0 + srow) * DIM_ + scol;
    const unsigned short* gBu = wup   + (n0 + srow) * DIM_ + scol;
    const unsigned short* gBg = wgate + (n0 + srow) * DIM_ + scol;

    STAGE_UG(0, 0);
    STAGE_UG(1, 32);
    int cur = 0;
    for (int k0 = 64; k0 < DIM_; k0 += 32) {      // 30 iterations
        PIPE_BAR(3);
        const int nn = cur == 0 ? 2 : cur - 1;    // (cur+2)%3 — freed buffer
        STAGE_UG(nn, k0);
        COMPUTE_UG(cur);
        cur = cur == 2 ? 0 : cur + 1;
    }
    PIPE_BAR(3);
    COMPUTE_UG(cur);                 // step 30
    cur = cur == 2 ? 0 : cur + 1;
    PIPE_BAR(0);
    COMPUTE_UG(cur);                 // step 31

    for (int im = 0; im < 2; ++im) {
        for (int in = 0; in < 2; ++in) {
            const int n = n0 + wn + in * 16 + lr;
            const float ub = up_bias[n], gb = gate_bias[n];
            for (int r = 0; r < 4; ++r) {
                const int m = m0 + wm + im * 16 + lkq * 4 + r;
                const float u = au[im][in][r] + ub;
                const float g = ag[im][in][r] + gb;
                const float h = (u / (1.f + __expf(-u))) * g;
                hid[m * HIDDEN_ + n] = f2bf(h);
            }
        }
    }
}

// ---------------------------------------------------------------- down GEMM
// BK=32, 3-deep (24KB), split-K=4 (grid 512 = 2/CU; atomics halved vs splitK8).
// atomicAdd epilogue onto d_out (pre-initialized to x + down_bias).
#define STAGE_DN(buf, k0)                                      \
    async16(gA + (k0), sA + (buf) * 2048 + t * 8);             \
    async16(gB + (k0), sB + (buf) * 2048 + t * 8);

#define COMPUTE_DN(buf)                                                        \
    {                                                                          \
        const int kb = (buf) * 2048 + lkq * 8;                                 \
        short8 a[2], b2[2];                                                    \
        _Pragma("unroll")                                                      \
        for (int im = 0; im < 2; ++im)                                         \
            a[im] = *(const short8*)&sA[kb + (wm + im * 16 + lr) * 32];        \
        _Pragma("unroll")                                                      \
        for (int in = 0; in < 2; ++in)                                         \
            b2[in] = *(const short8*)&sB[kb + (wn + in * 16 + lr) * 32];       \
        _Pragma("unroll")                                                      \
        for (int im = 0; im < 2; ++im)                                         \
            _Pragma("unroll")                                                  \
            for (int in = 0; in < 2; ++in)                                     \
                acc[im][in] = __builtin_amdgcn_mfma_f32_16x16x32_bf16(         \
                    a[im], b2[in], acc[im][in], 0, 0, 0);                      \
    }

__global__ __launch_bounds__(256) void gemm_down_kernel(
    const unsigned short* __restrict__ hid,     // [512][4096]
    const unsigned short* __restrict__ wdown,   // [1024][4096]
    float* __restrict__ out) {                  // [512][1024]
    __shared__ __align__(16) unsigned short sA[3 * 2048];   // 12 KB
    __shared__ __align__(16) unsigned short sB[3 * 2048];   // 12 KB
    const int t = threadIdx.x;
    const int n0 = blockIdx.x * 64;
    const int m0 = blockIdx.y * 64;
    const int kb0 = blockIdx.z * 1024;          // split-K = 4
    const int w = t >> 6, l = t & 63;
    const int wm = (w >> 1) * 32, wn = (w & 1) * 32;
    const int lr = l & 15, lkq = (l >> 4);

    float4v acc[2][2];
    for (int im = 0; im < 2; ++im)
        for (int in = 0; in < 2; ++in)
            acc[im][in] = float4v{0.f, 0.f, 0.f, 0.f};

    const int srow = t >> 2, scol = (t & 3) * 8;
    const unsigned short* gA = hid   + (m0 + srow) * HIDDEN_ + scol;
    const unsigned short* gB = wdown + (n0 + srow) * HIDDEN_ + scol;

    STAGE_DN(0, kb0);
    STAGE_DN(1, kb0 + 32);
    int cur = 0;
    for (int k0 = kb0 + 64; k0 < kb0 + 1024; k0 += 32) {   // 30 iterations
        PIPE_BAR(2);
        const int nn = cur == 0 ? 2 : cur - 1;
        STAGE_DN(nn, k0);
        COMPUTE_DN(cur);
        cur = cur == 2 ? 0 : cur + 1;
    }
    PIPE_BAR(2);
    COMPUTE_DN(cur);                 // step 30
    cur = cur == 2 ? 0 : cur + 1;
    PIPE_BAR(0);
    COMPUTE_DN(cur);                 // step 31

    for (int im = 0; im < 2; ++im) {
        for (int in = 0; in < 2; ++in) {
            const int n = n0 + wn + in * 16 + lr;
            for (int r = 0; r < 4; ++r) {
                const int m = m0 + wm + im * 16 + lkq * 4 + r;
                atomicAdd(out + m * DIM_ + n, acc[im][in][r]);
            }
        }
    }
}

// ---------------------------------------------------------------- launch
extern "C" void kernel_launch(void* const* d_in, const int* in_sizes, int n_in,
                              void* d_out, int out_size, void* d_ws, size_t ws_size,
                              hipStream_t stream) {
    const float* x         = (const float*)d_in[0];
    const int*   up_row    = (const int*)d_in[1];
    const int*   up_col    = (const int*)d_in[2];
    const float* up_val    = (const float*)d_in[3];
    const float* up_bias   = (const float*)d_in[4];
    const int*   gate_row  = (const int*)d_in[5];
    const int*   gate_col  = (const int*)d_in[6];
    const float* gate_val  = (const float*)d_in[7];
    const float* gate_bias = (const float*)d_in[8];
    const int*   down_row  = (const int*)d_in[9];
    const int*   down_col  = (const int*)d_in[10];
    const float* down_val  = (const float*)d_in[11];
    const float* down_bias = (const float*)d_in[12];
    float* out = (float*)d_out;

    unsigned char* ws = (unsigned char*)d_ws;
    unsigned short* WUP   = (unsigned short*)(ws);
    unsigned short* WGATE = (unsigned short*)(ws + (8u << 20));
    unsigned short* WDOWN = (unsigned short*)(ws + (16u << 20));
    unsigned short* XB    = (unsigned short*)(ws + (24u << 20));
    unsigned short* HID   = (unsigned short*)(ws + (25u << 20));
    unsigned int*   BANDS = (unsigned int*)(ws + (29u << 20));
    int*            CNT   = (int*)(ws + (66u << 20));
    int*            OCNT  = (int*)(ws + (67u << 20));
    uint2*          GOF   = (uint2*)(ws + (67u << 20) + 4096);

    bin_prep_kernel<<<1024, 256, 0, stream>>>(
        up_row, up_col, up_val, gate_row, gate_col, gate_val,
        down_row, down_col, down_val, x, down_bias, BANDS, CNT, OCNT, GOF, XB, out);

    build_ug_kernel<<<1024, 512, 0, stream>>>(BANDS, CNT, OCNT, GOF, WUP, WGATE);

    fused_upgate_builddown_kernel<<<1024, 256, 0, stream>>>(
        XB, WUP, WGATE, up_bias, gate_bias, HID, BANDS, CNT, OCNT, GOF, WDOWN);

    gemm_down_kernel<<<dim3(DIM_ / 64, TTOK_ / 64, 4), 256, 0, stream>>>(
        HID, WDOWN, out);
}